// Round 5
// baseline (531.020 us; speedup 1.0000x reference)
//
#include <hip/hip_runtime.h>
#include <hip/hip_bf16.h>

// Action_Prediction: 3-layer MLP (relu) -> scalar logit -> per-segment softmax
// -> Gumbel-max sample. N=524288, B=4096 segments of 128 contiguous nodes.
//
// R7: R6 + explicit software pipelining of the barrier-free k-loops.
// R6 post-mortem: MFMA busy (27% = 74us) == the 32x32 floor; ~155us is wait,
// dominated by same-step ds_read_b128 -> MFMA dependency (~120-150cyc LDS
// latency vs 64cyc MFMA per k-step, only 2 waves/SIMD to cover it).
//  - do_layer: B-frags prefetched 1 k-step ahead (4 named bf16x8);
//    A-frags (global, L2 ~200cyc) prefetched 2 steps ahead (3-deep rotate).
//  - do_layer0 unchanged (chunk barriers make cross-step prefetch unsafe).
//
// d_ws layout: W0t bf16 [n=256][k=128]; W1t [256][256]; W2t [256][256]
// (n-major so weight A-frags are contiguous 16B).

#define NFULL 524288
#define BSEG  4096
#define SEGSZ 128
#define DIN   128
#define HID   256
#define MROWS 128
#define KPAD  264   // LDS row stride (bf16): 528B = 33 granules -> bank-balanced

typedef __bf16 bf16x8 __attribute__((ext_vector_type(8)));
typedef float  f32x16 __attribute__((ext_vector_type(16)));

#define MFMA32(a, b, c) __builtin_amdgcn_mfma_f32_32x32x16_bf16((a), (b), (c), 0, 0, 0)

__device__ __forceinline__ unsigned short f2bf(float f) {
  __hip_bfloat16 h = __float2bfloat16(f);
  return __builtin_bit_cast(unsigned short, h);
}

// ------------------------------------------------- weight transpose+convert
__global__ __launch_bounds__(256) void convert_weights(
    const float* __restrict__ W0, const float* __restrict__ W1,
    const float* __restrict__ W2,
    unsigned short* __restrict__ W0t, unsigned short* __restrict__ W1t,
    unsigned short* __restrict__ W2t) {
  const int tid = blockIdx.x * 256 + threadIdx.x;
  if (tid < 32768) {                     // W0 [k=128][n=256] -> W0t[n][k]
    const int n = tid >> 7, k = tid & 127;
    W0t[tid] = f2bf(W0[k * 256 + n]);
  } else if (tid < 98304) {              // W1 [256][256]
    const int u = tid - 32768;
    const int n = u >> 8, k = u & 255;
    W1t[u] = f2bf(W1[k * 256 + n]);
  } else if (tid < 163840) {             // W2 [256][256]
    const int u = tid - 98304;
    const int n = u >> 8, k = u & 255;
    W2t[u] = f2bf(W2[k * 256 + n]);
  }
}

// ---------------------------------------------------------------- MFMA core
// 32x32x16: A-frag lane l: A[m = l&31][k = (l>>5)*8 + j] (16B contiguous k).
// B-frag lane l: B[k = (l>>5)*8 + j][n = l&31] -> Abuf row (node), contig k.
// C/D lane l, reg r: col = l&31 (node), row = (r&3) + 8*(r>>2) + 4*(l>>5)
// (feat)  [guide §3, m74/m101-verified; R6 bench passed => layout confirmed].

__device__ __forceinline__ void init_acc(const float* __restrict__ bias,
                                         int wm, int h, f32x16 (&acc)[2][4]) {
  #pragma unroll
  for (int mt = 0; mt < 2; ++mt) {
    f32x16 c;
    #pragma unroll
    for (int g = 0; g < 4; ++g) {
      const float4 bv = *(const float4*)&bias[wm * 64 + mt * 32 + 8 * g + 4 * h];
      c[4 * g + 0] = bv.x; c[4 * g + 1] = bv.y;
      c[4 * g + 2] = bv.z; c[4 * g + 3] = bv.w;
    }
    #pragma unroll
    for (int nt = 0; nt < 4; ++nt) acc[mt][nt] = c;
  }
}

// Software-pipelined layer: B-frags (LDS) 1 step ahead, A-frags (global/L2)
// 2 steps ahead. K-loop is barrier-free, so the prefetch distance is real
// slack (unlike the m97-GEMM case where the barrier drain nulled it).
template<int K>
__device__ __forceinline__ void do_layer(
    const unsigned short* Abuf, const unsigned short* __restrict__ Wt,
    const float* __restrict__ bias, int wm, int lane, f32x16 (&acc)[2][4]) {
  constexpr int S = K / 16;
  const int l31 = lane & 31, h = lane >> 5;
  init_acc(bias, wm, h, acc);
  const unsigned short* Wb = Wt + (size_t)(wm * 64 + l31) * K + h * 8;
  const unsigned short* Ab = Abuf + (size_t)l31 * KPAD + h * 8;

  // A: cur (s), n1 (s+1); B: cur (s)
  bf16x8 ac0 = *(const bf16x8*)(Wb);
  bf16x8 ac1 = *(const bf16x8*)(Wb + 32 * K);
  bf16x8 a10, a11;
  if (S > 1) {
    a10 = *(const bf16x8*)(Wb + 16);
    a11 = *(const bf16x8*)(Wb + 32 * K + 16);
  }
  bf16x8 b0 = *(const bf16x8*)(Ab + 0 * 32 * KPAD);
  bf16x8 b1 = *(const bf16x8*)(Ab + 1 * 32 * KPAD);
  bf16x8 b2 = *(const bf16x8*)(Ab + 2 * 32 * KPAD);
  bf16x8 b3 = *(const bf16x8*)(Ab + 3 * 32 * KPAD);

  #pragma unroll
  for (int s = 0; s < S; ++s) {
    bf16x8 a20, a21, bn0, bn1, bn2, bn3;
    if (s + 2 < S) {                    // issue A(s+2): global, L2 ~200cyc
      a20 = *(const bf16x8*)(Wb + (s + 2) * 16);
      a21 = *(const bf16x8*)(Wb + 32 * K + (s + 2) * 16);
    }
    if (s + 1 < S) {                    // issue B(s+1): LDS, ~120cyc
      bn0 = *(const bf16x8*)(Ab + 0 * 32 * KPAD + (s + 1) * 16);
      bn1 = *(const bf16x8*)(Ab + 1 * 32 * KPAD + (s + 1) * 16);
      bn2 = *(const bf16x8*)(Ab + 2 * 32 * KPAD + (s + 1) * 16);
      bn3 = *(const bf16x8*)(Ab + 3 * 32 * KPAD + (s + 1) * 16);
    }
    __builtin_amdgcn_s_setprio(1);
    acc[0][0] = MFMA32(ac0, b0, acc[0][0]);
    acc[1][0] = MFMA32(ac1, b0, acc[1][0]);
    acc[0][1] = MFMA32(ac0, b1, acc[0][1]);
    acc[1][1] = MFMA32(ac1, b1, acc[1][1]);
    acc[0][2] = MFMA32(ac0, b2, acc[0][2]);
    acc[1][2] = MFMA32(ac1, b2, acc[1][2]);
    acc[0][3] = MFMA32(ac0, b3, acc[0][3]);
    acc[1][3] = MFMA32(ac1, b3, acc[1][3]);
    __builtin_amdgcn_s_setprio(0);
    if (s + 1 < S) {
      ac0 = a10; ac1 = a11; a10 = a20; a11 = a21;
      b0 = bn0; b1 = bn1; b2 = bn2; b3 = bn3;
    }
  }
}

// L0 with fused chunked X staging. Chunk c = k in [32c, 32c+32).
// Thread t stages row (t>>1), 16 floats at k-offset (t&1)*16.
// Pipeline: load(c+1) issued before MFMA(c); cvt+write(c+1) after; barrier.
__device__ __forceinline__ void do_layer0(
    unsigned short* Abuf, const float* __restrict__ Xr,
    const unsigned short* __restrict__ Wt, const float* __restrict__ bias,
    int wm, int lane, int tid, f32x16 (&acc)[2][4]) {
  const int l31 = lane & 31, h = lane >> 5;
  const int sr = tid >> 1, sk = (tid & 1) * 16;
  const float* Xp = Xr + (size_t)sr * DIN + sk;
  unsigned short* Sp = Abuf + sr * KPAD + sk;

  float4 V[4][4];
  #pragma unroll
  for (int i = 0; i < 4; ++i) V[1][i] = *(const float4*)(Xp + 32 + i * 4);
  #pragma unroll
  for (int i = 0; i < 4; ++i) V[0][i] = *(const float4*)(Xp + i * 4);
  #pragma unroll
  for (int i = 0; i < 4; ++i) {           // store chunk 0
    ushort4 p;
    p.x = f2bf(V[0][i].x); p.y = f2bf(V[0][i].y);
    p.z = f2bf(V[0][i].z); p.w = f2bf(V[0][i].w);
    *(ushort4*)(Sp + i * 4) = p;
  }
  __syncthreads();

  init_acc(bias, wm, h, acc);
  const unsigned short* Wb = Wt + (size_t)(wm * 64 + l31) * DIN + h * 8;
  const unsigned short* Ab = Abuf + (size_t)l31 * KPAD + h * 8;
  bf16x8 a0 = *(const bf16x8*)(Wb);
  bf16x8 a1 = *(const bf16x8*)(Wb + 32 * DIN);

  #pragma unroll
  for (int s = 0; s < 8; ++s) {           // k16-step; chunk = s>>1
    bf16x8 an0, an1;
    if (s < 7) {
      an0 = *(const bf16x8*)(Wb + (s + 1) * 16);
      an1 = *(const bf16x8*)(Wb + 32 * DIN + (s + 1) * 16);
    }
    if (s == 1) {                         // issue loads chunk 2
      #pragma unroll
      for (int i = 0; i < 4; ++i) V[2][i] = *(const float4*)(Xp + 64 + i * 4);
    }
    if (s == 3) {                         // issue loads chunk 3
      #pragma unroll
      for (int i = 0; i < 4; ++i) V[3][i] = *(const float4*)(Xp + 96 + i * 4);
    }
    bf16x8 b[4];
    #pragma unroll
    for (int nt = 0; nt < 4; ++nt)
      b[nt] = *(const bf16x8*)(Ab + nt * 32 * KPAD + s * 16);
    __builtin_amdgcn_s_setprio(1);
    #pragma unroll
    for (int nt = 0; nt < 4; ++nt) {
      acc[0][nt] = MFMA32(a0, b[nt], acc[0][nt]);
      acc[1][nt] = MFMA32(a1, b[nt], acc[1][nt]);
    }
    __builtin_amdgcn_s_setprio(0);
    if (s == 1 || s == 3 || s == 5) {     // cvt+write chunk c+1
      const int c = (s >> 1) + 1;
      #pragma unroll
      for (int i = 0; i < 4; ++i) {
        ushort4 p;
        p.x = f2bf(V[c][i].x); p.y = f2bf(V[c][i].y);
        p.z = f2bf(V[c][i].z); p.w = f2bf(V[c][i].w);
        *(ushort4*)(Sp + c * 32 + i * 4) = p;
      }
      __syncthreads();
    }
    if (s < 7) { a0 = an0; a1 = an1; }
  }
}

// writeback: lane holds 4 consecutive feats per reg-quad at fixed node ->
// ushort4 per (mt,nt,g): 32 ds_write_b64/thread.
__device__ __forceinline__ void writeback_relu(
    unsigned short* Abuf, int wm, int lane, const f32x16 (&acc)[2][4]) {
  const int l31 = lane & 31, h = lane >> 5;
  #pragma unroll
  for (int nt = 0; nt < 4; ++nt) {
    const int node = nt * 32 + l31;
    #pragma unroll
    for (int mt = 0; mt < 2; ++mt) {
      #pragma unroll
      for (int g = 0; g < 4; ++g) {
        const int feat = wm * 64 + mt * 32 + 8 * g + 4 * h;
        ushort4 p;
        p.x = f2bf(fmaxf(acc[mt][nt][4 * g + 0], 0.f));
        p.y = f2bf(fmaxf(acc[mt][nt][4 * g + 1], 0.f));
        p.z = f2bf(fmaxf(acc[mt][nt][4 * g + 2], 0.f));
        p.w = f2bf(fmaxf(acc[mt][nt][4 * g + 3], 0.f));
        *(ushort4*)&Abuf[node * KPAD + feat] = p;
      }
    }
  }
}

// ------------------------------------------------------------------ sampling
__device__ __forceinline__ void threefry2x32_42(unsigned x0, unsigned x1,
                                                unsigned& o0, unsigned& o1) {
  const unsigned ks0 = 0u, ks1 = 42u;
  const unsigned ks2 = ks0 ^ ks1 ^ 0x1BD11BDAu;
  x0 += ks0; x1 += ks1;
#define TF_R(r) { x0 += x1; x1 = (x1 << (r)) | (x1 >> (32 - (r))); x1 ^= x0; }
  TF_R(13) TF_R(15) TF_R(26) TF_R(6)   x0 += ks1; x1 += ks2 + 1u;
  TF_R(17) TF_R(29) TF_R(16) TF_R(24)  x0 += ks2; x1 += ks0 + 2u;
  TF_R(13) TF_R(15) TF_R(26) TF_R(6)   x0 += ks0; x1 += ks1 + 3u;
  TF_R(17) TF_R(29) TF_R(16) TF_R(24)  x0 += ks1; x1 += ks2 + 4u;
  TF_R(13) TF_R(15) TF_R(26) TF_R(6)   x0 += ks2; x1 += ks0 + 5u;
#undef TF_R
  o0 = x0; o1 = x1;
}

// -------------------------------------------------------------- fused kernel
__global__ __launch_bounds__(256, 2) void mlp_fused(
    const float* __restrict__ X,
    const unsigned short* __restrict__ W0t,
    const unsigned short* __restrict__ W1t,
    const unsigned short* __restrict__ W2t,
    const float* __restrict__ b0, const float* __restrict__ b1,
    const float* __restrict__ b2,
    const float* __restrict__ Wf, const float* __restrict__ bfp,
    float* __restrict__ out) {
  __shared__ alignas(16) unsigned short Abuf[MROWS * KPAD];  // 66 KB
  __shared__ float WfS[HID];
  __shared__ float Lpart[4][MROWS];
  __shared__ float red2[2];
  __shared__ float smax_sh[2];
  __shared__ int   sidx_sh[2];
  __shared__ float probs_sh[SEGSZ];

  const int tid  = threadIdx.x;
  const int lane = tid & 63;
  const int wm   = tid >> 6;     // 0..3: feature group (64 feats), all nodes
  const int l31  = lane & 31;
  const int h    = lane >> 5;
  const size_t row0 = (size_t)blockIdx.x * MROWS;

  if (tid < HID) WfS[tid] = Wf[tid];

  f32x16 acc[2][4];
  do_layer0(Abuf, X + row0 * DIN, W0t, b0, wm, lane, tid, acc);   // h0 (stage fused)
  __syncthreads();
  writeback_relu(Abuf, wm, lane, acc);
  __syncthreads();
  do_layer<HID>(Abuf, W1t, b1, wm, lane, acc);   // h1
  __syncthreads();
  writeback_relu(Abuf, wm, lane, acc);
  __syncthreads();
  do_layer<HID>(Abuf, W2t, b2, wm, lane, acc);   // h2 (pre-relu, in regs)

  // head: logit[node] = sum_feat relu(h2[feat][node]) * Wf[feat] + bf.
  // Lane holds feats wm*64+mt*32+(r&3)+8*(r>>2)+4h at nodes nt*32+l31.
  #pragma unroll
  for (int nt = 0; nt < 4; ++nt) {
    float sv = 0.f;
    #pragma unroll
    for (int mt = 0; mt < 2; ++mt)
      #pragma unroll
      for (int r = 0; r < 16; ++r)
        sv = fmaf(fmaxf(acc[mt][nt][r], 0.f),
                  WfS[wm * 64 + mt * 32 + (r & 3) + 8 * (r >> 2) + 4 * h], sv);
    sv += __shfl_xor(sv, 32, 64);          // combine the two feat-halves
    if (h == 0) Lpart[wm][nt * 32 + l31] = sv;
  }
  __syncthreads();

  // fused per-segment softmax + Gumbel-max (segment == this block's 128 rows)
  float e = 0.f, prob = 0.f;
  if (tid < SEGSZ) {
    const float lg = Lpart[0][tid] + Lpart[1][tid] + Lpart[2][tid] +
                     Lpart[3][tid] + bfp[0];
    e = expf(lg);
    float v = e;
    #pragma unroll
    for (int off = 32; off >= 1; off >>= 1) v += __shfl_xor(v, off, 64);
    if ((tid & 63) == 0) red2[tid >> 6] = v;
  }
  __syncthreads();
  if (tid < SEGSZ) {
    const float S = red2[0] + red2[1];
    prob = e / S;
    probs_sh[tid] = prob;
    unsigned o0, o1;
    threefry2x32_42(0u, (unsigned)(row0 + (size_t)tid), o0, o1);
    const float f = __uint_as_float(0x3f800000u | (o0 >> 9)) - 1.0f;
    const float u = fmaxf(1e-20f, f + 1e-20f);
    const float g = -logf(-logf(u));
    float ms = logf(prob) + g;
    int   mi = (int)row0 + tid;
    #pragma unroll
    for (int off = 1; off < 64; off <<= 1) {
      const float os = __shfl_xor(ms, off, 64);
      const int   oi = __shfl_xor(mi, off, 64);
      if (os > ms || (os == ms && oi > mi)) { ms = os; mi = oi; }
    }
    if ((tid & 63) == 0) { smax_sh[tid >> 6] = ms; sidx_sh[tid >> 6] = mi; }
  }
  __syncthreads();
  if (tid == 0) {
    const float s0 = smax_sh[0], s1 = smax_sh[1];
    const int   i0 = sidx_sh[0], i1 = sidx_sh[1];
    const int win = (s1 > s0 || (s1 == s0 && i1 > i0)) ? i1 : i0;
    const int s = blockIdx.x;
    out[s]            = probs_sh[win - (int)row0];
    out[BSEG + s]     = (float)(win - (int)row0);
    out[2 * BSEG + s] = (float)win;
  }
}

extern "C" void kernel_launch(void* const* d_in, const int* in_sizes, int n_in,
                              void* d_out, int out_size, void* d_ws, size_t ws_size,
                              hipStream_t stream) {
  const float* X  = (const float*)d_in[0];
  const float* W0 = (const float*)d_in[1];
  const float* b0 = (const float*)d_in[2];
  const float* W1 = (const float*)d_in[3];
  const float* b1 = (const float*)d_in[4];
  const float* W2 = (const float*)d_in[5];
  const float* b2 = (const float*)d_in[6];
  const float* Wf = (const float*)d_in[7];
  const float* bf = (const float*)d_in[8];

  unsigned short* W0t = (unsigned short*)d_ws;
  unsigned short* W1t = W0t + 256 * 128;
  unsigned short* W2t = W1t + 256 * 256;
  float* out = (float*)d_out;

  convert_weights<<<640, 256, 0, stream>>>(W0, W1, W2, W0t, W1t, W2t);
  mlp_fused<<<BSEG, 256, 0, stream>>>(X, W0t, W1t, W2t, b0, b1, b2,
                                      Wf, bf, out);
}